// Round 4
// baseline (354.239 us; speedup 1.0000x reference)
//
#include <hip/hip_runtime.h>

// MultiHeadAttention: B=4, T=2048, D=1024, H=16, HD=64, causal.
// cvt x->bf16; cvt+transpose W; m97-style async GEMM (QKV); V-transpose kernel;
// barrier-free flash (1 wave = 32-query strip, 32x32x16 MFMA, in-register P
// transpose via perm+shfl, no-max softmax); m97-style GEMM (proj).

typedef unsigned short u16;
typedef unsigned int u32;
typedef __attribute__((ext_vector_type(8))) short short8;    // 8 x bf16 MFMA operand
typedef __attribute__((ext_vector_type(4))) float f32x4;
typedef __attribute__((ext_vector_type(16))) float f32x16;   // 32x32 MFMA accumulator

#define SCLOG 0.1803368801111444f   // log2(e) / 8  (folds 1/sqrt(64) into exp2 arg)
#define MASKV (-1e30f)

__device__ __forceinline__ u16 f2bf(float f) {
  union { float f; u32 u; } x; x.f = f;
  u32 r = x.u + 0x7FFFu + ((x.u >> 16) & 1u);   // RNE
  return (u16)(r >> 16);
}

__device__ __forceinline__ void async16(const u16* g, u16* l) {
  __builtin_amdgcn_global_load_lds((__attribute__((address_space(1))) void*)g,
                                   (__attribute__((address_space(3))) void*)l,
                                   16, 0, 0);
}

// ---------------- convert x: fp32 -> bf16 ----------------
__global__ void cvt_x_kernel(const float* __restrict__ x, u16* __restrict__ xb) {
  size_t i = ((size_t)blockIdx.x * 256 + threadIdx.x) * 4;
  float4 v = *(const float4*)(x + i);
  uint2 o;
  o.x = (u32)f2bf(v.x) | ((u32)f2bf(v.y) << 16);
  o.y = (u32)f2bf(v.z) | ((u32)f2bf(v.w) << 16);
  *(uint2*)(xb + i) = o;
}

// ------- convert + transpose weight: src[K][N] fp32 -> dst[N][K] bf16 -------
__global__ void cvt_tr_kernel(const float* __restrict__ src, u16* __restrict__ dst,
                              int K, int N) {
  __shared__ float tile[32][33];
  int n0 = blockIdx.x * 32, k0 = blockIdx.y * 32;
  int tx = threadIdx.x & 31, ty = threadIdx.x >> 5;
  #pragma unroll
  for (int r = ty; r < 32; r += 8)
    tile[r][tx] = src[(size_t)(k0 + r) * N + n0 + tx];
  __syncthreads();
  #pragma unroll
  for (int r = ty; r < 32; r += 8)
    dst[(size_t)(n0 + r) * K + k0 + tx] = f2bf(tile[tx][r]);
}

// ---------------- GEMM (unchanged, known-good m97 pattern) ----------------
template<bool BF16OUT>
__global__ __launch_bounds__(256) void gemm_bt(const u16* __restrict__ A,
                                               const u16* __restrict__ Bt,
                                               const float* __restrict__ bias,
                                               void* __restrict__ Cv, int N) {
  constexpr int K = 1024;
  __shared__ alignas(16) u16 As[128 * 32];
  __shared__ alignas(16) u16 Bs[128 * 32];
  const int t = threadIdx.x;
  const int w = t >> 6, lane = t & 63, quad = lane >> 4, l15 = lane & 15;
  const int m0 = blockIdx.y * 128, n0 = blockIdx.x * 128;
  const int wm = (w >> 1) * 64, wn = (w & 1) * 64;

  size_t gA[2], gB[2];
  int lds_st[2];
  #pragma unroll
  for (int ii = 0; ii < 2; ii++) {
    const int row = w * 32 + ii * 16 + (lane >> 2);
    const int db = (lane & 3) ^ (row & 3);
    gA[ii] = (size_t)(m0 + row) * K + db * 8;
    gB[ii] = (size_t)(n0 + row) * K + db * 8;
    lds_st[ii] = (w * 32 + ii * 16) * 32 + lane * 8;
  }
  const int fsw = (quad ^ (l15 & 3)) << 3;

  f32x4 acc[4][4];
  #pragma unroll
  for (int i = 0; i < 4; i++)
    #pragma unroll
    for (int j = 0; j < 4; j++)
      acc[i][j] = (f32x4){0.f, 0.f, 0.f, 0.f};

  for (int k0 = 0; k0 < K; k0 += 32) {
    __syncthreads();
    async16(A + gA[0] + k0, As + lds_st[0]);
    async16(A + gA[1] + k0, As + lds_st[1]);
    async16(Bt + gB[0] + k0, Bs + lds_st[0]);
    async16(Bt + gB[1] + k0, Bs + lds_st[1]);
    __syncthreads();
    short8 af[4], bf[4];
    #pragma unroll
    for (int i = 0; i < 4; i++)
      af[i] = *(const short8*)(As + (wm + i * 16 + l15) * 32 + fsw);
    #pragma unroll
    for (int j = 0; j < 4; j++)
      bf[j] = *(const short8*)(Bs + (wn + j * 16 + l15) * 32 + fsw);
    #pragma unroll
    for (int i = 0; i < 4; i++)
      #pragma unroll
      for (int j = 0; j < 4; j++)
        acc[i][j] = __builtin_amdgcn_mfma_f32_16x16x32_bf16(af[i], bf[j], acc[i][j], 0, 0, 0);
  }
  #pragma unroll
  for (int j = 0; j < 4; j++) {
    const int col = n0 + wn + j * 16 + l15;
    const float bv = bias[col];
    #pragma unroll
    for (int i = 0; i < 4; i++) {
      const int row = m0 + wm + i * 16 + quad * 4;
      #pragma unroll
      for (int r = 0; r < 4; r++) {
        float v = acc[i][j][r] + bv;
        if (BF16OUT) ((u16*)Cv)[(size_t)(row + r) * N + col] = f2bf(v);
        else         ((float*)Cv)[(size_t)(row + r) * N + col] = v;
      }
    }
  }
}

// -------- V transpose: qkv V-part [t][d] -> vt[bh][d][t] (bf16) --------
// grid (32 t-tiles, 64 bh). Conflict-free XOR-swizzled LDS transpose.
__global__ __launch_bounds__(256) void vt_kernel(const u16* __restrict__ qkv,
                                                 u16* __restrict__ vt) {
  __shared__ alignas(16) u16 L[64 * 64];
  const int t = threadIdx.x;
  const int w = t >> 6, lane = t & 63;
  const int bh = blockIdx.y;
  const int b = bh >> 4, h = bh & 15;
  const int t0 = blockIdx.x * 64;
  const u16* Vg = qkv + (size_t)b * 2048 * 3072 + 2048 + h * 64;
  const int vkey = w * 8 + (lane >> 3);      // t-row within tile
  const int vchunk = lane & 7;               // 16B chunk of d
  int4 v0 = *(const int4*)(Vg + (size_t)(t0 + vkey) * 3072 + vchunk * 8);
  int4 v1 = *(const int4*)(Vg + (size_t)(t0 + vkey + 32) * 3072 + vchunk * 8);
  union { int4 v; u16 u[8]; } uv;
  #pragma unroll
  for (int rd = 0; rd < 2; rd++) {
    uv.v = rd ? v1 : v0;
    const int kb = w + 4 * rd, ko = lane >> 3;
    #pragma unroll
    for (int j = 0; j < 8; j++)    // L[d][t-local], chunk swizzle (g^(d>>3)^(d&7))&7
      L[(vchunk * 8 + j) * 64 + (((kb ^ vchunk ^ j) & 7) << 3) + ko] = uv.u[j];
  }
  __syncthreads();
  const int d = t >> 2;
  #pragma unroll
  for (int gg = 0; gg < 2; gg++) {
    const int g = (t & 3) * 2 + gg;
    const int phys = (g ^ (d >> 3) ^ (d & 7)) & 7;
    int4 val = *(const int4*)(L + d * 64 + phys * 8);
    *(int4*)(vt + ((size_t)bh * 64 + d) * 2048 + t0 + g * 8) = val;
  }
}

// ---------------- flash attention: barrier-free, 1 wave = 32-q strip ----------------
// S^T = K·Q^T via 32x32x16 MFMA (C: col=lane&31=q, row=(reg&3)+8*(reg>>2)+4*(lane>>5)=key).
// P^T B-frags built in-register (perm pack + half-wave shfl). O^T = V^T·P^T accumulated
// in C-layout; l = plain sum (no-max softmax) + one final shfl. LDS only for O transpose
// in the epilogue (per-wave 4KB buffer). Robust to A/B k-slot permutation: both PV
// operands assign key = base + half*8 + j to the same slot.
__global__ __launch_bounds__(256) void flash_kernel(const u16* __restrict__ qkv,
                                                    const u16* __restrict__ vt,
                                                    u16* __restrict__ attn) {
  constexpr int T = 2048, N3 = 3072;
  __shared__ alignas(16) u16 Ob[4][32 * 64];
  const int t = threadIdx.x;
  const int w = t >> 6, lane = t & 63;
  const int col = lane & 31, half = lane >> 5;
  const int bh = blockIdx.x, b = bh >> 4, h = bh & 15;
  const int s = (15 - (int)blockIdx.y) * 4 + w;      // strip: heavy (large s) first
  const int s32 = s * 32;
  const u16* base = qkv + (size_t)b * T * N3 + h * 64;
  const u16* Kg = base + 1024;
  const u16* Vt = vt + (size_t)bh * 64 * 2048;

  // Q fragments (B-operand): slot(half,j) -> d = kk*16 + half*8 + j
  short8 qf[4];
  {
    const u16* qrow = base + (size_t)(s32 + col) * N3 + half * 8;
    #pragma unroll
    for (int kk = 0; kk < 4; kk++)
      qf[kk] = *(const short8*)(qrow + kk * 16);
  }

  f32x16 o[2];
  o[0] = (f32x16)(0.f);
  o[1] = (f32x16)(0.f);
  float l_acc = 0.f;

  const int ntiles = (s >> 1) + 1;
  for (int kt = 0; kt < ntiles; ++kt) {
    #pragma unroll
    for (int st = 0; st < 2; st++) {
      const int keybase = kt * 64 + st * 32;
      if (keybase > s32) break;                     // fully-masked subtile (wave-uniform)
      // K fragments (A-operand): m=key=col, slot -> d = kk*16 + half*8 + j
      const u16* krow = Kg + (size_t)(keybase + col) * N3 + half * 8;
      short8 kf[4];
      #pragma unroll
      for (int kk = 0; kk < 4; kk++)
        kf[kk] = *(const short8*)(krow + kk * 16);
      // S^T = K · Q^T
      f32x16 S = (f32x16)(0.f);
      #pragma unroll
      for (int kk = 0; kk < 4; kk++)
        S = __builtin_amdgcn_mfma_f32_32x32x16_bf16(kf[kk], qf[kk], S, 0, 0, 0);
      union { f32x16 v; u32 u[16]; float f[16]; } su;
      su.v = S;
      if (keybase == s32) {                         // diagonal subtile: mask key>query
        #pragma unroll
        for (int i = 0; i < 16; i++) {
          const int kl = (i & 3) + 8 * (i >> 2) + 4 * half;
          if (kl > col) su.f[i] = MASKV;
        }
      }
      // p = exp2(s/8*log2e); l from truncated-bf16 values (consistent with packed P)
      #pragma unroll
      for (int i = 0; i < 16; i++) {
        const float p = __builtin_amdgcn_exp2f(fminf(su.f[i], 240.f) * SCLOG);
        union { float f; u32 u; } pc; pc.f = p;
        su.u[i] = pc.u;
        union { u32 u; float f; } tr; tr.u = pc.u & 0xFFFF0000u;
        l_acc += tr.f;
      }
      // pack reg pairs (trunc to bf16): pk[b*2+c] = pack(reg (2c+1)|(b<<2), reg (2c)|(b<<2))
      u32 pk[8], xp[8];
      #pragma unroll
      for (int bq = 0; bq < 4; bq++)
        #pragma unroll
        for (int c = 0; c < 2; c++)
          pk[bq * 2 + c] = __builtin_amdgcn_perm(su.u[(bq << 2) + (c << 1) + 1],
                                                 su.u[(bq << 2) + (c << 1)], 0x07060302u);
      #pragma unroll
      for (int i = 0; i < 8; i++)
        xp[i] = (u32)__shfl_xor((int)pk[i], 32, 64);
      // V^T fragments + PV accumulate: contraction slot -> key = keybase + cc*16 + half*8 + j
      #pragma unroll
      for (int cc = 0; cc < 2; cc++) {
        union { u32 d[4]; short8 s8; } pf;
        pf.d[0] = half ? xp[4 * cc + 2] : pk[4 * cc];
        pf.d[1] = half ? xp[4 * cc + 3] : pk[4 * cc + 1];
        pf.d[2] = half ? pk[4 * cc + 2] : xp[4 * cc];
        pf.d[3] = half ? pk[4 * cc + 3] : xp[4 * cc + 1];
        #pragma unroll
        for (int dt = 0; dt < 2; dt++) {
          const short8 vf = *(const short8*)(Vt + (size_t)(dt * 32 + col) * 2048 +
                                             keybase + cc * 16 + half * 8);
          o[dt] = __builtin_amdgcn_mfma_f32_32x32x16_bf16(vf, pf.s8, o[dt], 0, 0, 0);
        }
      }
    }
  }

  // l across lane halves (each half summed a disjoint key set)
  const float l_tot = l_acc + (float)__shfl_xor(l_acc, 32, 64);
  const float inv = 1.0f / l_tot;

  // epilogue: O^T (C-layout) -> per-wave LDS [q][d] (chunk-XOR swizzle) -> coalesced store
  u16* buf = Ob[w];
  #pragma unroll
  for (int dt = 0; dt < 2; dt++)
    #pragma unroll
    for (int i = 0; i < 16; i++) {
      const int d = dt * 32 + (i & 3) + 8 * (i >> 2) + 4 * half;
      buf[col * 64 + ((((d >> 3) ^ (col & 7)) & 7) << 3) + (d & 7)] = f2bf(o[dt][i] * inv);
    }
  __syncthreads();
  {
    const int qr = lane >> 1;
    const size_t orow = (size_t)(b * T + s32 + qr) * 1024 + h * 64;
    #pragma unroll
    for (int ccs = 0; ccs < 4; ccs++) {
      const int c = (lane & 1) * 4 + ccs;
      const int phys = (c ^ (qr & 7)) & 7;
      int4 val = *(const int4*)(buf + qr * 64 + phys * 8);
      *(int4*)(attn + orow + c * 8) = val;
    }
  }
}

extern "C" void kernel_launch(void* const* d_in, const int* in_sizes, int n_in,
                              void* d_out, int out_size, void* d_ws, size_t ws_size,
                              hipStream_t stream) {
  (void)in_sizes; (void)n_in; (void)out_size; (void)ws_size;
  const float* x     = (const float*)d_in[0];
  // d_in[1]: causal mask — statically tril, handled in-kernel
  const float* w_qkv = (const float*)d_in[2];
  const float* b_qkv = (const float*)d_in[3];
  const float* w_out = (const float*)d_in[4];
  const float* b_out = (const float*)d_in[5];
  float* out = (float*)d_out;

  char* ws = (char*)d_ws;
  u16* xb    = (u16*)(ws);                 // 8192*1024 bf16 = 16.78 MB (reused as attnb)
  u16* wqkvT = (u16*)(ws + 16777216);      // 3072*1024 bf16 =  6.29 MB
  u16* woutT = (u16*)(ws + 23068672);      // 1024*1024 bf16 =  2.10 MB
  u16* qkvb  = (u16*)(ws + 25165824);      // 8192*3072 bf16 = 50.33 MB
  u16* vtb   = (u16*)(ws + 75497472);      // 64*64*2048 bf16 = 33.55 MB (tot 109.1 MB)
  u16* attnb = xb;                         // xb is dead after the QKV GEMM

  cvt_x_kernel<<<8192, 256, 0, stream>>>(x, xb);
  cvt_tr_kernel<<<dim3(96, 32), 256, 0, stream>>>(w_qkv, wqkvT, 1024, 3072);
  cvt_tr_kernel<<<dim3(32, 32), 256, 0, stream>>>(w_out, woutT, 1024, 1024);
  gemm_bt<true ><<<dim3(24, 64), 256, 0, stream>>>(xb, wqkvT, b_qkv, qkvb, 3072);
  vt_kernel<<<dim3(32, 64), 256, 0, stream>>>(qkvb, vtb);
  flash_kernel<<<dim3(64, 16), 256, 0, stream>>>(qkvb, vtb, attnb);
  gemm_bt<false><<<dim3(8, 64), 256, 0, stream>>>(attnb, woutT, b_out, out, 1024);
}

// Round 6
// 289.143 us; speedup vs baseline: 1.2251x; 1.2251x over previous
//
#include <hip/hip_runtime.h>

// MultiHeadAttention: B=4, T=2048, D=1024, H=16, HD=64, causal.
// cvt x->bf16; cvt+transpose W; m97-style async GEMM (QKV); flash attention
// (BQ=64 blocks, one q-tile per block, full k-range, heavy-first LPT, LDS-staged
// DMA pipeline, no-max softmax, MFMA row-sum, direct epilogue); GEMM (proj).

typedef unsigned short u16;
typedef unsigned int u32;
typedef __attribute__((ext_vector_type(8))) short short8;   // 8 x bf16 MFMA operand
typedef __attribute__((ext_vector_type(4))) float f32x4;    // MFMA accumulator

#define MASKV (-1e30f)
#define SCLOG 0.1803368801111444f   // log2(e)/8  (folds 1/sqrt(64) into exp2 arg)

__device__ __forceinline__ u16 f2bf(float f) {
  union { float f; u32 u; } x; x.f = f;
  u32 r = x.u + 0x7FFFu + ((x.u >> 16) & 1u);   // RNE
  return (u16)(r >> 16);
}

__device__ __forceinline__ void async16(const u16* g, u16* l) {
  __builtin_amdgcn_global_load_lds((__attribute__((address_space(1))) void*)g,
                                   (__attribute__((address_space(3))) void*)l,
                                   16, 0, 0);
}

// ---------------- convert x: fp32 -> bf16 ----------------
__global__ void cvt_x_kernel(const float* __restrict__ x, u16* __restrict__ xb) {
  size_t i = ((size_t)blockIdx.x * 256 + threadIdx.x) * 4;
  float4 v = *(const float4*)(x + i);
  uint2 o;
  o.x = (u32)f2bf(v.x) | ((u32)f2bf(v.y) << 16);
  o.y = (u32)f2bf(v.z) | ((u32)f2bf(v.w) << 16);
  *(uint2*)(xb + i) = o;
}

// ------- convert + transpose weight: src[K][N] fp32 -> dst[N][K] bf16 -------
__global__ void cvt_tr_kernel(const float* __restrict__ src, u16* __restrict__ dst,
                              int K, int N) {
  __shared__ float tile[32][33];
  int n0 = blockIdx.x * 32, k0 = blockIdx.y * 32;
  int tx = threadIdx.x & 31, ty = threadIdx.x >> 5;
  #pragma unroll
  for (int r = ty; r < 32; r += 8)
    tile[r][tx] = src[(size_t)(k0 + r) * N + n0 + tx];
  __syncthreads();
  #pragma unroll
  for (int r = ty; r < 32; r += 8)
    dst[(size_t)(n0 + r) * K + k0 + tx] = f2bf(tile[tx][r]);
}

// ---------------- GEMM (unchanged, known-good m97 pattern) ----------------
template<bool BF16OUT>
__global__ __launch_bounds__(256) void gemm_bt(const u16* __restrict__ A,
                                               const u16* __restrict__ Bt,
                                               const float* __restrict__ bias,
                                               void* __restrict__ Cv, int N) {
  constexpr int K = 1024;
  __shared__ alignas(16) u16 As[128 * 32];
  __shared__ alignas(16) u16 Bs[128 * 32];
  const int t = threadIdx.x;
  const int w = t >> 6, lane = t & 63, quad = lane >> 4, l15 = lane & 15;
  const int m0 = blockIdx.y * 128, n0 = blockIdx.x * 128;
  const int wm = (w >> 1) * 64, wn = (w & 1) * 64;

  size_t gA[2], gB[2];
  int lds_st[2];
  #pragma unroll
  for (int ii = 0; ii < 2; ii++) {
    const int row = w * 32 + ii * 16 + (lane >> 2);
    const int db = (lane & 3) ^ (row & 3);
    gA[ii] = (size_t)(m0 + row) * K + db * 8;
    gB[ii] = (size_t)(n0 + row) * K + db * 8;
    lds_st[ii] = (w * 32 + ii * 16) * 32 + lane * 8;
  }
  const int fsw = (quad ^ (l15 & 3)) << 3;

  f32x4 acc[4][4];
  #pragma unroll
  for (int i = 0; i < 4; i++)
    #pragma unroll
    for (int j = 0; j < 4; j++)
      acc[i][j] = (f32x4){0.f, 0.f, 0.f, 0.f};

  for (int k0 = 0; k0 < K; k0 += 32) {
    __syncthreads();
    async16(A + gA[0] + k0, As + lds_st[0]);
    async16(A + gA[1] + k0, As + lds_st[1]);
    async16(Bt + gB[0] + k0, Bs + lds_st[0]);
    async16(Bt + gB[1] + k0, Bs + lds_st[1]);
    __syncthreads();
    short8 af[4], bf[4];
    #pragma unroll
    for (int i = 0; i < 4; i++)
      af[i] = *(const short8*)(As + (wm + i * 16 + l15) * 32 + fsw);
    #pragma unroll
    for (int j = 0; j < 4; j++)
      bf[j] = *(const short8*)(Bs + (wn + j * 16 + l15) * 32 + fsw);
    #pragma unroll
    for (int i = 0; i < 4; i++)
      #pragma unroll
      for (int j = 0; j < 4; j++)
        acc[i][j] = __builtin_amdgcn_mfma_f32_16x16x32_bf16(af[i], bf[j], acc[i][j], 0, 0, 0);
  }
  #pragma unroll
  for (int j = 0; j < 4; j++) {
    const int col = n0 + wn + j * 16 + l15;
    const float bv = bias[col];
    #pragma unroll
    for (int i = 0; i < 4; i++) {
      const int row = m0 + wm + i * 16 + quad * 4;
      #pragma unroll
      for (int r = 0; r < 4; r++) {
        float v = acc[i][j][r] + bv;
        if (BF16OUT) ((u16*)Cv)[(size_t)(row + r) * N + col] = f2bf(v);
        else         ((float*)Cv)[(size_t)(row + r) * N + col] = v;
      }
    }
  }
}

// ---------------- flash attention, causal ----------------
// Block = (bh, qt): 64 queries (4 waves x 16), FULL k-range 0..qt. Heavy q-tiles
// dispatch first (LPT backfill across 2048 blocks). r3-proven pipeline: K async-DMA
// dbuf (source-permuted swizzle), V reg-prefetch + conflict-free transpose scatter,
// P via per-wave swizzled LDS, no-max softmax, MFMA row-sum l, direct store o/l.
__global__ __launch_bounds__(256) void flash_kernel(const u16* __restrict__ qkv,
                                                    u16* __restrict__ attn) {
  constexpr int T = 2048, N3 = 3072;
  __shared__ alignas(16) u16 Ks[2][64 * 64];
  __shared__ alignas(16) u16 VsT[2][64 * 64];
  __shared__ alignas(16) u16 Ps[4][16 * 64];
  const int t = threadIdx.x;
  const int w = t >> 6, lane = t & 63, quad = lane >> 4, l15 = lane & 15;
  const int bh = blockIdx.x, b = bh >> 4, h = bh & 15;
  const int qt = 31 - (int)blockIdx.y;          // heavy tiles first
  const int qw = qt * 64 + w * 16;

  const u16* base = qkv + (size_t)b * T * N3 + h * 64;
  const u16* Kg = base + 1024;
  const u16* Vg = base + 2048;

  // K async staging: wave w, 2 instrs, 8 keys x 128B each; source chunk permuted
  size_t gK[2];
  int ldsK[2];
  #pragma unroll
  for (int ii = 0; ii < 2; ii++) {
    const int key0 = w * 16 + ii * 8;
    const int key = key0 + (lane >> 3);
    const int db = ((lane & 7) ^ (key0 >> 3) ^ (lane >> 3)) & 7;
    gK[ii] = (size_t)key * N3 + db * 8;
    ldsK[ii] = key0 * 64 + lane * 8;
  }
  // V staging: lane loads V[vkey][vchunk*8..+7]
  const int vkey = w * 8 + (lane >> 3);
  const int vchunk = lane & 7;
  const size_t gV = (size_t)vkey * N3 + vchunk * 8;

  short8 onesf;
  #pragma unroll
  for (int j = 0; j < 8; j++) onesf[j] = (short)0x3F80;   // bf16 1.0

  // Q fragments: A[m=l15][k=quad*8+j], 2 d-chunks
  short8 qf[2];
  #pragma unroll
  for (int kc = 0; kc < 2; kc++)
    qf[kc] = *(const short8*)(base + (size_t)(qw + l15) * N3 + kc * 32 + quad * 8);

  f32x4 o[4], lac;
  lac = (f32x4){0.f, 0.f, 0.f, 0.f};
  #pragma unroll
  for (int dt = 0; dt < 4; dt++) o[dt] = (f32x4){0.f, 0.f, 0.f, 0.f};

  // preload tile 0
  async16(Kg + gK[0], &Ks[0][ldsK[0]]);
  async16(Kg + gK[1], &Ks[0][ldsK[1]]);
  {
    int4 vp0 = *(const int4*)(Vg + gV);
    int4 vp1 = *(const int4*)(Vg + gV + (size_t)32 * N3);
    union { int4 v; u16 u[8]; } uv;
    #pragma unroll
    for (int rd = 0; rd < 2; rd++) {
      uv.v = rd ? vp1 : vp0;
      const int kb = w + 4 * rd, ko = lane >> 3;
      #pragma unroll
      for (int j = 0; j < 8; j++)
        VsT[0][(vchunk * 8 + j) * 64 + (((kb ^ vchunk ^ j) & 7) << 3) + ko] = uv.u[j];
    }
  }

  int cur = 0;
  for (int kt = 0; kt <= qt; ++kt) {
    __syncthreads();   // drains K-DMA(kt); scatters + prior-iter reads visible
    const u16* Kc = Ks[cur];
    const u16* Vc = VsT[cur];
    u16* pw = Ps[w];
    short8 kf[4][2];
    #pragma unroll
    for (int nt = 0; nt < 4; nt++) {
      const int kx = (nt * 2 + (l15 >> 3)) ^ (l15 & 7);
      #pragma unroll
      for (int ks = 0; ks < 2; ks++)
        kf[nt][ks] = *(const short8*)(Kc + (nt * 16 + l15) * 64 +
                                      ((((ks * 4 + quad) ^ kx) & 7) << 3));
    }
    int4 vp0, vp1;
    if (kt < qt) {   // prefetch tile kt+1
      const size_t koff = (size_t)(kt + 1) * 64 * N3;
      async16(Kg + koff + gK[0], &Ks[cur ^ 1][ldsK[0]]);
      async16(Kg + koff + gK[1], &Ks[cur ^ 1][ldsK[1]]);
      vp0 = *(const int4*)(Vg + koff + gV);
      vp1 = *(const int4*)(Vg + koff + gV + (size_t)32 * N3);
    }

    // S = Q K^T
    f32x4 s[4];
    #pragma unroll
    for (int nt = 0; nt < 4; nt++) s[nt] = (f32x4){0.f, 0.f, 0.f, 0.f};
    #pragma unroll
    for (int nt = 0; nt < 4; nt++)
      #pragma unroll
      for (int kc = 0; kc < 2; kc++)
        s[nt] = __builtin_amdgcn_mfma_f32_16x16x32_bf16(qf[kc], kf[nt][kc], s[nt], 0, 0, 0);

    if (kt == qt) {   // diagonal tile: causal mask
      #pragma unroll
      for (int r = 0; r < 4; r++) {
        const int row = qw + quad * 4 + r;
        #pragma unroll
        for (int nt = 0; nt < 4; nt++) {
          const int col = kt * 64 + nt * 16 + l15;
          if (col > row) s[nt][r] = MASKV;
        }
      }
    }
    // p = exp2(s*log2e/8) -> truncated bf16 -> per-wave swizzled LDS (A-layout)
    #pragma unroll
    for (int nt = 0; nt < 4; nt++) {
      const int lc = nt * 2 + (l15 >> 3);
      #pragma unroll
      for (int r = 0; r < 4; r++) {
        const int rl = quad * 4 + r;
        const float p = __builtin_amdgcn_exp2f(fminf(s[nt][r], 240.f) * SCLOG);
        union { float f; u32 u; } pc; pc.f = p;
        const int fp_ = (rl ^ (rl >> 1)) & 7;
        pw[rl * 64 + (((lc ^ fp_) & 7) << 3) + (l15 & 7)] = (u16)(pc.u >> 16);
      }
    }
    // O += P V ; l += P 1   (Gray swizzle on P reads)
    const int fpr = (l15 ^ (l15 >> 1)) & 7;
    #pragma unroll
    for (int ks = 0; ks < 2; ks++) {
      const int cb = ks * 4 + quad;
      short8 pf = *(const short8*)(pw + l15 * 64 + (((cb ^ fpr) & 7) << 3));
      #pragma unroll
      for (int dt = 0; dt < 4; dt++) {
        const int vx = (dt * 2 + (l15 >> 3)) ^ (l15 & 7);
        short8 vf = *(const short8*)(Vc + (dt * 16 + l15) * 64 + (((cb ^ vx) & 7) << 3));
        o[dt] = __builtin_amdgcn_mfma_f32_16x16x32_bf16(pf, vf, o[dt], 0, 0, 0);
      }
      lac = __builtin_amdgcn_mfma_f32_16x16x32_bf16(pf, onesf, lac, 0, 0, 0);
    }

    if (kt < qt) {  // transpose-scatter V(kt+1) into other buffer
      u16* Vn = (u16*)VsT[cur ^ 1];
      union { int4 v; u16 u[8]; } uv;
      #pragma unroll
      for (int rd = 0; rd < 2; rd++) {
        uv.v = rd ? vp1 : vp0;
        const int kb = w + 4 * rd, ko = lane >> 3;
        #pragma unroll
        for (int j = 0; j < 8; j++)
          Vn[(vchunk * 8 + j) * 64 + (((kb ^ vchunk ^ j) & 7) << 3) + ko] = uv.u[j];
      }
    }
    cur ^= 1;
  }

  // normalize + store bf16 [B*T][D]  (every lane's lac[r] holds the row sum)
  #pragma unroll
  for (int r = 0; r < 4; r++) {
    const float invl = 1.0f / lac[r];
    const int row = qw + quad * 4 + r;
    const size_t off = (size_t)(b * T + row) * 1024 + h * 64;
    #pragma unroll
    for (int dt = 0; dt < 4; dt++)
      attn[off + dt * 16 + l15] = f2bf(o[dt][r] * invl);
  }
}

extern "C" void kernel_launch(void* const* d_in, const int* in_sizes, int n_in,
                              void* d_out, int out_size, void* d_ws, size_t ws_size,
                              hipStream_t stream) {
  (void)in_sizes; (void)n_in; (void)out_size; (void)ws_size;
  const float* x     = (const float*)d_in[0];
  // d_in[1]: causal mask — statically tril, handled in-kernel
  const float* w_qkv = (const float*)d_in[2];
  const float* b_qkv = (const float*)d_in[3];
  const float* w_out = (const float*)d_in[4];
  const float* b_out = (const float*)d_in[5];
  float* out = (float*)d_out;

  char* ws = (char*)d_ws;
  u16* xb    = (u16*)(ws);                 // 8192*1024 bf16 = 16.78 MB (reused as attnb)
  u16* wqkvT = (u16*)(ws + 16777216);      // 3072*1024 bf16 =  6.29 MB
  u16* woutT = (u16*)(ws + 23068672);      // 1024*1024 bf16 =  2.10 MB
  u16* qkvb  = (u16*)(ws + 25165824);      // 8192*3072 bf16 = 50.33 MB
  u16* attnb = xb;                         // xb dead after QKV GEMM

  cvt_x_kernel<<<8192, 256, 0, stream>>>(x, xb);
  cvt_tr_kernel<<<dim3(96, 32), 256, 0, stream>>>(w_qkv, wqkvT, 1024, 3072);
  cvt_tr_kernel<<<dim3(32, 32), 256, 0, stream>>>(w_out, woutT, 1024, 1024);
  gemm_bt<true ><<<dim3(24, 64), 256, 0, stream>>>(xb, wqkvT, b_qkv, qkvb, 3072);
  flash_kernel<<<dim3(64, 32), 256, 0, stream>>>(qkvb, attnb);
  gemm_bt<false><<<dim3(8, 64), 256, 0, stream>>>(attnb, woutT, b_out, out, 1024);
}